// Round 6
// baseline (286.674 us; speedup 1.0000x reference)
//
#include <hip/hip_runtime.h>
#include <hip/hip_bf16.h>

// Problem geometry
#define E_CNT  256
#define D_IN   15
#define HDIM   128
#define BATCH  8192
#define CPE    (BATCH / 32)         // 256 chunks of 32 rows per expert
#define SW1    24                   // w1t row stride in shorts (48B)
#define SW2    152                  // w2t row stride in shorts (304B): 128 W2T + b2@128 + 0-pad
#define NL2E   -1.44269504088896341f

typedef float f32x16 __attribute__((ext_vector_type(16)));
typedef short bf16x8 __attribute__((ext_vector_type(8)));
typedef unsigned int uint4v __attribute__((ext_vector_type(4)));

#define MFMA(a, b, c) __builtin_amdgcn_mfma_f32_32x32x16_bf16((a), (b), (c), 0, 0, 0)

// bf16 via round-half-up on the bit pattern (values finite here).
static __device__ inline unsigned short f2bf_rnd(float f) {
    unsigned u = __builtin_bit_cast(unsigned, f);
    return (unsigned short)((u + 0x8000u) >> 16);
}

// sigmoid with pre-scaled input az = -z*log2(e): s = rcp(1 + 2^az).
static __device__ inline float sg(float az) {
    float e = __builtin_amdgcn_exp2f(az);
    return __builtin_amdgcn_rcpf(1.0f + e);
}

// pack two floats to a bf16 pair (lo in low half), round-half-up.
// v_perm_b32 merges the two high halves in one op: 3 VALU total.
static __device__ inline unsigned pack2(float lo, float hi_) {
    unsigned a = __builtin_bit_cast(unsigned, lo) + 0x8000u;
    unsigned b = __builtin_bit_cast(unsigned, hi_) + 0x8000u;
#if __has_builtin(__builtin_amdgcn_perm)
    return __builtin_amdgcn_perm(b, a, 0x07060302u);   // D = {a.b2,a.b3,b.b2,b.b3}
#else
    return (a >> 16) | (b & 0xffff0000u);
#endif
}

// v_permlane32_swap_b32 a, b:
// after: a = {lanes<32: a_lo, lanes>=32: b_lo}; b = {lanes<32: a_hi, lanes>=32: b_hi}
static __device__ inline void pl32swap(unsigned &a, unsigned &b) {
#if __has_builtin(__builtin_amdgcn_permlane32_swap)
    auto r = __builtin_amdgcn_permlane32_swap(a, b, false, false);
    a = (unsigned)r[0];
    b = (unsigned)r[1];
#else
    asm volatile("v_permlane32_swap_b32 %0, %1" : "+v"(a), "+v"(b));
#endif
}

static __device__ inline f32x16 zero16() {
    f32x16 z;
#pragma unroll
    for (int i = 0; i < 16; ++i) z[i] = 0.0f;
    return z;
}

// From a 32x32 C-tile accumulator (col = lane&31 = batch, row = (reg&3)+8*(reg>>2)+4*(lane>>5))
// holding pre-scaled pre-activations, apply sigmoid and produce two B-frags
// (k = 16t + (lane>>5)*8 + j) covering tile rows 0..15 (f0) and 16..31 (f1).
static __device__ inline void sig_pack(const f32x16 a, bf16x8 &f0, bf16x8 &f1) {
    unsigned s01 = pack2(sg(a[0]),  sg(a[1]));
    unsigned s23 = pack2(sg(a[2]),  sg(a[3]));
    unsigned s45 = pack2(sg(a[4]),  sg(a[5]));
    unsigned s67 = pack2(sg(a[6]),  sg(a[7]));
    unsigned s89 = pack2(sg(a[8]),  sg(a[9]));
    unsigned sAB = pack2(sg(a[10]), sg(a[11]));
    unsigned sCD = pack2(sg(a[12]), sg(a[13]));
    unsigned sEF = pack2(sg(a[14]), sg(a[15]));
    pl32swap(s01, s45);
    pl32swap(s23, s67);
    pl32swap(s89, sCD);
    pl32swap(sAB, sEF);
    uint4v t0 = {s01, s23, s45, s67};
    uint4v t1 = {s89, sAB, sCD, sEF};
    f0 = __builtin_bit_cast(bf16x8, t0);
    f1 = __builtin_bit_cast(bf16x8, t1);
}

// x[B][15] f32 -> xbf[B][16] bf16 with slot 15 = 1.0 (b1 partner)
__global__ __launch_bounds__(256)
void prep_x_kernel(const float* __restrict__ x, unsigned short* __restrict__ xbf)
{
    int i = blockIdx.x * 256 + threadIdx.x;
    if (i >= BATCH * 16) return;
    int row = i >> 4, k = i & 15;
    float v = (k < D_IN) ? x[row * D_IN + k] : 1.0f;
    xbf[i] = f2bf_rnd(v);
}

// Single-chunk, phase-structured MFMA MLP. L1 is processed per mf-tile so at
// most one f32x16 L1 accumulator is live; L2+L3 keep c2+o3 (32 AGPR). Peak
// unified register use ~125 -> fits 3 waves/EU (cap 170) without spill.
__global__ __launch_bounds__(256, 3)
void mlp256_kernel(const float* __restrict__ x, const unsigned short* __restrict__ xbf,
                   const float* __restrict__ W1, const float* __restrict__ b1,
                   const float* __restrict__ W2, const float* __restrict__ b2,
                   const float* __restrict__ W3, const float* __restrict__ b3,
                   float* __restrict__ dst, int use_xbf, int transposed)
{
    __shared__ __align__(16) unsigned short w1t[HDIM * SW1];   // W1^T (+b1 at k=15), scaled
    __shared__ __align__(16) unsigned short w2t[HDIM * SW2];   // W2^T scaled + b2 pad at col 128
    __shared__ __align__(16) unsigned short w3l[2 * HDIM];     // w3 then 128 zeros (A-frag rows 1..31)

    const int tid  = threadIdx.x;
    const int wave = tid >> 6;
    const int lane = tid & 63;
    const int l31  = lane & 31;
    const int hi   = lane >> 5;

    // grid = 768: e = bid&255, rg = bid>>8 (0..2). Blocks e, e+256, e+512 share
    // bid%8 -> same XCD under round-robin dispatch: one expert's W2 in one L2.
    const int bid = blockIdx.x;
    const int e   = bid & 255;
    const int rg  = bid >> 8;                 // chunk residue class mod 3

    const float* w1p = W1 + e * (D_IN * HDIM);
    const float* b1p = b1 + e * HDIM;
    const float* w2p = W2 + e * (HDIM * HDIM);
    const float* b2p = b2 + e * HDIM;
    const float* w3p = W3 + e * HDIM;
    const float  b3v = b3[e];

    // ---- stage weights (prologue only) ----
    for (int i = tid; i < HDIM * 16; i += 256) {
        int h = i & 127, k = i >> 7;
        float v = (k < D_IN) ? w1p[k * HDIM + h] : b1p[h];
        w1t[h * SW1 + k] = f2bf_rnd(v * NL2E);
    }
    for (int i = tid; i < HDIM * HDIM; i += 256) {
        int h = i & 127, k = i >> 7;
        w2t[h * SW2 + k] = f2bf_rnd(w2p[k * HDIM + h] * NL2E);
    }
    for (int i = tid; i < HDIM * 16; i += 256) {
        int h = i >> 4, kk = i & 15;
        w2t[h * SW2 + 128 + kk] = (kk == 0) ? f2bf_rnd(b2p[h] * NL2E) : (unsigned short)0;
    }
    for (int i = tid; i < 2 * HDIM; i += 256)
        w3l[i] = (i < HDIM) ? f2bf_rnd(w3p[i]) : (unsigned short)0;

    bf16x8 ONEB;   // B-frag with 1.0 at k'==0 (partners the b2 K-step)
#pragma unroll
    for (int j = 0; j < 8; ++j) ONEB[j] = 0;
    if (hi == 0) ONEB[0] = (short)0x3F80;

    __syncthreads();   // weights staged; waves independent from here

    // W3 A-frag base: row l31==0 lanes read w3, all other rows read the zero区
    const unsigned short* w3base = w3l + ((l31 == 0) ? 0 : HDIM) + hi * 8;

    // chunks: c ≡ rg (mod 3), distributed over the 4 waves
    for (int c = rg + 3 * wave; c < CPE; c += 12) {
        const int bb = c * 32 + l31;

        // x B-frag: col b = l31, k = hi*8+j (slot 15 = 1.0)
        bf16x8 XB;
        if (use_xbf) {
            XB = *reinterpret_cast<const bf16x8*>(xbf + (size_t)bb * 16 + hi * 8);
        } else {
            const float* xp = x + (size_t)bb * D_IN;
#pragma unroll
            for (int j = 0; j < 8; ++j) {
                int k = hi * 8 + j;
                XB[j] = (short)f2bf_rnd((k < D_IN) ? xp[k] : 1.0f);
            }
        }

        // ---- layer 1, per mf-tile (a1 dies immediately into h-frags) ----
        bf16x8 h[8];
#pragma unroll
        for (int mf = 0; mf < 4; ++mf) {
            bf16x8 wa = *reinterpret_cast<const bf16x8*>(w1t + (mf * 32 + l31) * SW1 + hi * 8);
            f32x16 a1 = MFMA(wa, XB, zero16());
            sig_pack(a1, h[2 * mf], h[2 * mf + 1]);
        }

        // ---- layer 2 + partial layer 3, per mf-tile ----
        f32x16 o3 = zero16();
#pragma unroll
        for (int mf = 0; mf < 4; ++mf) {
            bf16x8 wb = *reinterpret_cast<const bf16x8*>(w2t + (mf * 32 + l31) * SW2 + 128 + hi * 8);
            f32x16 c2 = MFMA(wb, ONEB, zero16());   // b2 bias K-step
#pragma unroll
            for (int ks = 0; ks < 8; ++ks) {
                bf16x8 wa = *reinterpret_cast<const bf16x8*>(w2t + (mf * 32 + l31) * SW2 + ks * 16 + hi * 8);
                c2 = MFMA(wa, h[ks], c2);
            }
            bf16x8 g0, g1;
            sig_pack(c2, g0, g1);
#pragma unroll
            for (int t = 0; t < 2; ++t) {
                bf16x8 w3f = *reinterpret_cast<const bf16x8*>(w3base + (2 * mf + t) * 16);
                o3 = MFMA(w3f, (t ? g1 : g0), o3);
            }
        }

        if (hi == 0) {
            float v = o3[0] + b3v;   // output row 0 = reg 0, hi==0 lanes
            if (transposed) dst[(size_t)e * BATCH + bb] = v;
            else            dst[(size_t)bb * E_CNT + e] = v;
        }
    }
}

// wsT[e][b] (256 x 8192) -> out[b][e] (8192 x 256), 64x64 LDS tiles
__global__ __launch_bounds__(256)
void transpose_out_kernel(const float* __restrict__ wsT, float* __restrict__ out)
{
    __shared__ float tile[64][65];
    const int tx = threadIdx.x & 63;
    const int ty = threadIdx.x >> 6;
    const int b0 = blockIdx.x * 64;
    const int e0 = blockIdx.y * 64;
#pragma unroll
    for (int r = ty; r < 64; r += 4)
        tile[r][tx] = wsT[(size_t)(e0 + r) * BATCH + b0 + tx];
    __syncthreads();
#pragma unroll
    for (int r = ty; r < 64; r += 4)
        out[(size_t)(b0 + r) * E_CNT + e0 + tx] = tile[tx][r];
}

extern "C" void kernel_launch(void* const* d_in, const int* in_sizes, int n_in,
                              void* d_out, int out_size, void* d_ws, size_t ws_size,
                              hipStream_t stream) {
    const float* x  = (const float*)d_in[0];
    const float* W1 = (const float*)d_in[1];
    const float* b1 = (const float*)d_in[2];
    const float* W2 = (const float*)d_in[3];
    const float* b2 = (const float*)d_in[4];
    const float* W3 = (const float*)d_in[5];
    const float* b3 = (const float*)d_in[6];
    float* out = (float*)d_out;

    const size_t XBF_BYTES = (size_t)BATCH * 16 * sizeof(unsigned short);  // 256 KB
    const size_t WST_BYTES = (size_t)E_CNT * BATCH * sizeof(float);        // 8 MB

    const bool have_xbf = ws_size >= XBF_BYTES + WST_BYTES;
    const bool have_wst = ws_size >= WST_BYTES;

    unsigned short* xbf = (unsigned short*)d_ws;
    float* wsT = have_xbf ? (float*)((char*)d_ws + XBF_BYTES) : (float*)d_ws;

    if (have_xbf)
        prep_x_kernel<<<dim3((BATCH * 16 + 255) / 256), dim3(256), 0, stream>>>(x, xbf);

    if (have_wst) {
        mlp256_kernel<<<dim3(E_CNT * 3), dim3(256), 0, stream>>>(
            x, xbf, W1, b1, W2, b2, W3, b3, wsT, have_xbf ? 1 : 0, 1);
        transpose_out_kernel<<<dim3(BATCH / 64, E_CNT / 64), dim3(256), 0, stream>>>(
            wsT, out);
    } else {
        mlp256_kernel<<<dim3(E_CNT * 3), dim3(256), 0, stream>>>(
            x, xbf, W1, b1, W2, b2, W3, b3, out, 0, 0);
    }
}

// Round 7
// 195.769 us; speedup vs baseline: 1.4643x; 1.4643x over previous
//
#include <hip/hip_runtime.h>
#include <hip/hip_bf16.h>

// Problem geometry
#define E_CNT  256
#define D_IN   15
#define HDIM   128
#define BATCH  8192
#define CPE    (BATCH / 32)         // 256 chunks of 32 rows per expert
#define SW1    24                   // w1t row stride in shorts (48B)
#define SW2    152                  // w2t row stride in shorts (304B): 128 W2T + b2@128 + 0-pad
#define NL2E   -1.44269504088896341f

typedef float f32x16 __attribute__((ext_vector_type(16)));
typedef short bf16x8 __attribute__((ext_vector_type(8)));
typedef unsigned int uint4v __attribute__((ext_vector_type(4)));

#define MFMA(a, b, c) __builtin_amdgcn_mfma_f32_32x32x16_bf16((a), (b), (c), 0, 0, 0)

// bf16 via round-half-up on the bit pattern (values finite here).
static __device__ inline unsigned short f2bf_rnd(float f) {
    unsigned u = __builtin_bit_cast(unsigned, f);
    return (unsigned short)((u + 0x8000u) >> 16);
}

// sigmoid with pre-scaled input az = -z*log2(e): s = rcp(1 + 2^az).
static __device__ inline float sg(float az) {
    float e = __builtin_amdgcn_exp2f(az);
    return __builtin_amdgcn_rcpf(1.0f + e);
}

// pack two floats to a bf16 pair (lo in low half), round-half-up: 3 VALU.
static __device__ inline unsigned pack2(float lo, float hi_) {
    unsigned a = __builtin_bit_cast(unsigned, lo) + 0x8000u;
    unsigned b = __builtin_bit_cast(unsigned, hi_) + 0x8000u;
#if __has_builtin(__builtin_amdgcn_perm)
    return __builtin_amdgcn_perm(b, a, 0x07060302u);   // D = {a.b2,a.b3,b.b2,b.b3}
#else
    return (a >> 16) | (b & 0xffff0000u);
#endif
}

// v_permlane32_swap_b32 a, b:
// after: a = {lanes<32: a_lo, lanes>=32: b_lo}; b = {lanes<32: a_hi, lanes>=32: b_hi}
static __device__ inline void pl32swap(unsigned &a, unsigned &b) {
#if __has_builtin(__builtin_amdgcn_permlane32_swap)
    auto r = __builtin_amdgcn_permlane32_swap(a, b, false, false);
    a = (unsigned)r[0];
    b = (unsigned)r[1];
#else
    asm volatile("v_permlane32_swap_b32 %0, %1" : "+v"(a), "+v"(b));
#endif
}

static __device__ inline f32x16 zero16() {
    f32x16 z;
#pragma unroll
    for (int i = 0; i < 16; ++i) z[i] = 0.0f;
    return z;
}

// From a 32x32 C-tile accumulator (col = lane&31 = batch, row = (reg&3)+8*(reg>>2)+4*(lane>>5))
// holding pre-scaled pre-activations, apply sigmoid and produce two B-frags
// (k = 16t + (lane>>5)*8 + j) covering tile rows 0..15 (f0) and 16..31 (f1).
static __device__ inline void sig_pack(const f32x16 a, bf16x8 &f0, bf16x8 &f1) {
    unsigned s01 = pack2(sg(a[0]),  sg(a[1]));
    unsigned s23 = pack2(sg(a[2]),  sg(a[3]));
    unsigned s45 = pack2(sg(a[4]),  sg(a[5]));
    unsigned s67 = pack2(sg(a[6]),  sg(a[7]));
    unsigned s89 = pack2(sg(a[8]),  sg(a[9]));
    unsigned sAB = pack2(sg(a[10]), sg(a[11]));
    unsigned sCD = pack2(sg(a[12]), sg(a[13]));
    unsigned sEF = pack2(sg(a[14]), sg(a[15]));
    pl32swap(s01, s45);
    pl32swap(s23, s67);
    pl32swap(s89, sCD);
    pl32swap(sAB, sEF);
    uint4v t0 = {s01, s23, s45, s67};
    uint4v t1 = {s89, sAB, sCD, sEF};
    f0 = __builtin_bit_cast(bf16x8, t0);
    f1 = __builtin_bit_cast(bf16x8, t1);
}

// x[B][15] f32 -> xbf[B][16] bf16 with slot 15 = 1.0 (b1 partner)
__global__ __launch_bounds__(256)
void prep_x_kernel(const float* __restrict__ x, unsigned short* __restrict__ xbf)
{
    int i = blockIdx.x * 256 + threadIdx.x;
    if (i >= BATCH * 16) return;
    int row = i >> 4, k = i & 15;
    float v = (k < D_IN) ? x[row * D_IN + k] : 1.0f;
    xbf[i] = f2bf_rnd(v);
}

// Software-pipelined dual-chunk MFMA MLP: while chunk i runs L2+L3 (MFMA/LDS
// pipes), chunk i+1 runs L1+sigmoid (trans pipe). Static hA/hB buffers; at
// (256,2) the ~165-reg peak fits the 256-reg cap with margin (no spill).
__global__ __launch_bounds__(256, 2)
void mlp256_kernel(const float* __restrict__ x, const unsigned short* __restrict__ xbf,
                   const float* __restrict__ W1, const float* __restrict__ b1,
                   const float* __restrict__ W2, const float* __restrict__ b2,
                   const float* __restrict__ W3, const float* __restrict__ b3,
                   float* __restrict__ dst, int use_xbf, int transposed)
{
    __shared__ __align__(16) unsigned short w1t[HDIM * SW1];   // W1^T (+b1 at k=15), scaled
    __shared__ __align__(16) unsigned short w2t[HDIM * SW2];   // W2^T scaled + b2 pad at col 128
    __shared__ __align__(16) unsigned short w3l[2 * HDIM];     // w3 then 128 zeros (A-frag rows 1..31)

    const int tid  = threadIdx.x;
    const int wave = tid >> 6;
    const int lane = tid & 63;
    const int l31  = lane & 31;
    const int hi   = lane >> 5;

    // grid = 512: e = bid&255, rg = bid>>8 (0..1). Blocks e and e+256 share
    // bid%8 -> same XCD under round-robin dispatch: one expert's W2 in one L2.
    const int bid = blockIdx.x;
    const int e   = bid & 255;
    const int rg  = bid >> 8;

    const float* w1p = W1 + e * (D_IN * HDIM);
    const float* b1p = b1 + e * HDIM;
    const float* w2p = W2 + e * (HDIM * HDIM);
    const float* b2p = b2 + e * HDIM;
    const float* w3p = W3 + e * HDIM;
    const float  b3v = b3[e];

    // ---- stage weights (prologue only) ----
    for (int i = tid; i < HDIM * 16; i += 256) {
        int h = i & 127, k = i >> 7;
        float v = (k < D_IN) ? w1p[k * HDIM + h] : b1p[h];
        w1t[h * SW1 + k] = f2bf_rnd(v * NL2E);
    }
    for (int i = tid; i < HDIM * HDIM; i += 256) {
        int h = i & 127, k = i >> 7;
        w2t[h * SW2 + k] = f2bf_rnd(w2p[k * HDIM + h] * NL2E);
    }
    for (int i = tid; i < HDIM * 16; i += 256) {
        int h = i >> 4, kk = i & 15;
        w2t[h * SW2 + 128 + kk] = (kk == 0) ? f2bf_rnd(b2p[h] * NL2E) : (unsigned short)0;
    }
    for (int i = tid; i < 2 * HDIM; i += 256)
        w3l[i] = (i < HDIM) ? f2bf_rnd(w3p[i]) : (unsigned short)0;

    bf16x8 ONEB;   // B-frag with 1.0 at k'==0 (partners the b2 K-step)
#pragma unroll
    for (int j = 0; j < 8; ++j) ONEB[j] = 0;
    if (hi == 0) ONEB[0] = (short)0x3F80;

    __syncthreads();   // weights staged; waves independent from here

    // W3 A-frag base: row l31==0 lanes read w3, all other rows read the zero pad
    const unsigned short* w3base = w3l + ((l31 == 0) ? 0 : HDIM) + hi * 8;

    // ---- pipeline stages as always-inline lambdas (static buffer names only) ----
    auto l1sig = [&](int cc, bf16x8 (&H)[8]) __attribute__((always_inline)) {
        const int bb = cc * 32 + l31;
        bf16x8 XB;
        if (use_xbf) {
            XB = *reinterpret_cast<const bf16x8*>(xbf + (size_t)bb * 16 + hi * 8);
        } else {
            const float* xp = x + (size_t)bb * D_IN;
#pragma unroll
            for (int j = 0; j < 8; ++j) {
                int k = hi * 8 + j;
                XB[j] = (short)f2bf_rnd((k < D_IN) ? xp[k] : 1.0f);
            }
        }
#pragma unroll
        for (int mf = 0; mf < 4; ++mf) {
            bf16x8 wa = *reinterpret_cast<const bf16x8*>(w1t + (mf * 32 + l31) * SW1 + hi * 8);
            f32x16 a1 = MFMA(wa, XB, zero16());
            sig_pack(a1, H[2 * mf], H[2 * mf + 1]);
        }
    };

    auto l2l3 = [&](int cc, bf16x8 (&H)[8]) __attribute__((always_inline)) {
        f32x16 o3 = zero16();
#pragma unroll
        for (int mf = 0; mf < 4; ++mf) {
            bf16x8 wb = *reinterpret_cast<const bf16x8*>(w2t + (mf * 32 + l31) * SW2 + 128 + hi * 8);
            f32x16 c2 = MFMA(wb, ONEB, zero16());   // b2 bias K-step
#pragma unroll
            for (int ks = 0; ks < 8; ++ks) {
                bf16x8 wa = *reinterpret_cast<const bf16x8*>(w2t + (mf * 32 + l31) * SW2 + ks * 16 + hi * 8);
                c2 = MFMA(wa, H[ks], c2);
            }
            bf16x8 g0, g1;
            sig_pack(c2, g0, g1);
#pragma unroll
            for (int t = 0; t < 2; ++t) {
                bf16x8 w3f = *reinterpret_cast<const bf16x8*>(w3base + (2 * mf + t) * 16);
                o3 = MFMA(w3f, (t ? g1 : g0), o3);
            }
        }
        if (hi == 0) {
            const int bb = cc * 32 + l31;
            float v = o3[0] + b3v;   // output row 0 = reg 0, hi==0 lanes
            if (transposed) dst[(size_t)e * BATCH + bb] = v;
            else            dst[(size_t)bb * E_CNT + e] = v;
        }
    };

    // 32 chunks per wave: c_k = c0 + 8k. Pipeline: L1sig(k+1) overlaps L2L3(k).
    const int c0 = rg + 2 * wave;
    bf16x8 hA[8], hB[8];

    l1sig(c0, hA);
#pragma unroll 1
    for (int j = 0; j < 15; ++j) {
        const int cb = c0 + 8 * (2 * j);
        l1sig(cb + 8,  hB);  l2l3(cb,     hA);
        l1sig(cb + 16, hA);  l2l3(cb + 8, hB);
    }
    l1sig(c0 + 8 * 31, hB);
    l2l3(c0 + 8 * 30, hA);
    l2l3(c0 + 8 * 31, hB);
}

// wsT[e][b] (256 x 8192) -> out[b][e] (8192 x 256), 64x64 LDS tiles
__global__ __launch_bounds__(256)
void transpose_out_kernel(const float* __restrict__ wsT, float* __restrict__ out)
{
    __shared__ float tile[64][65];
    const int tx = threadIdx.x & 63;
    const int ty = threadIdx.x >> 6;
    const int b0 = blockIdx.x * 64;
    const int e0 = blockIdx.y * 64;
#pragma unroll
    for (int r = ty; r < 64; r += 4)
        tile[r][tx] = wsT[(size_t)(e0 + r) * BATCH + b0 + tx];
    __syncthreads();
#pragma unroll
    for (int r = ty; r < 64; r += 4)
        out[(size_t)(b0 + r) * E_CNT + e0 + tx] = tile[tx][r];
}

extern "C" void kernel_launch(void* const* d_in, const int* in_sizes, int n_in,
                              void* d_out, int out_size, void* d_ws, size_t ws_size,
                              hipStream_t stream) {
    const float* x  = (const float*)d_in[0];
    const float* W1 = (const float*)d_in[1];
    const float* b1 = (const float*)d_in[2];
    const float* W2 = (const float*)d_in[3];
    const float* b2 = (const float*)d_in[4];
    const float* W3 = (const float*)d_in[5];
    const float* b3 = (const float*)d_in[6];
    float* out = (float*)d_out;

    const size_t XBF_BYTES = (size_t)BATCH * 16 * sizeof(unsigned short);  // 256 KB
    const size_t WST_BYTES = (size_t)E_CNT * BATCH * sizeof(float);        // 8 MB

    const bool have_xbf = ws_size >= XBF_BYTES + WST_BYTES;
    const bool have_wst = ws_size >= WST_BYTES;

    unsigned short* xbf = (unsigned short*)d_ws;
    float* wsT = have_xbf ? (float*)((char*)d_ws + XBF_BYTES) : (float*)d_ws;

    if (have_xbf)
        prep_x_kernel<<<dim3((BATCH * 16 + 255) / 256), dim3(256), 0, stream>>>(x, xbf);

    if (have_wst) {
        mlp256_kernel<<<dim3(E_CNT * 2), dim3(256), 0, stream>>>(
            x, xbf, W1, b1, W2, b2, W3, b3, wsT, have_xbf ? 1 : 0, 1);
        transpose_out_kernel<<<dim3(BATCH / 64, E_CNT / 64), dim3(256), 0, stream>>>(
            wsT, out);
    } else {
        mlp256_kernel<<<dim3(E_CNT * 2), dim3(256), 0, stream>>>(
            x, xbf, W1, b1, W2, b2, W3, b3, out, 0, 0);
    }
}